// Round 8
// baseline (166.405 us; speedup 1.0000x reference)
//
#include <hip/hip_runtime.h>
#include <hip/hip_bf16.h>

// MHA forward, MI355X gfx950.
// cvt (weights -> bf16) -> batched QKV proj GEMM (128x64 tiles, 1536 blocks,
// fused f32->bf16 A-staging, swizzled LDS, gll16 B) -> causal flash attn
// (swapped-QK in-register softmax + T13 defer-max + T5 setprio, T14
// reg-prefetch, XCD remap + LPT) -> out GEMM (m97 single-buf).
// HIDDEN=1024, HEADS=16, HEAD_DIM=64, B=2, S=2048.

typedef __attribute__((ext_vector_type(4))) float f32x4;
typedef __attribute__((ext_vector_type(8))) short bf16x8;
typedef unsigned short u16;

#define SEQ   2048
#define NH    16
#define HD    64
#define HID   1024
#define CEXP  0.1803368801f  // 0.125 * log2(e)
#define MEG   1048576u

// HW round-to-nearest-even f32->bf16.
static __device__ __forceinline__ u16 f2bf(float f) {
  union { __hip_bfloat16 h; u16 u; } c;
  c.h = __float2bfloat16(f);
  return c.u;
}

// XOR swizzle on 8-elem bf16 chunks within a 64-elem row (T2, G4).
static __device__ __forceinline__ int swz(int row, int col8) {
  return col8 ^ ((row & 7) << 3);
}

// async global->LDS, 16B/lane; lds dest wave-uniform base (guide §5).
static __device__ __forceinline__ void gll16(const void* g, void* l) {
  __builtin_amdgcn_global_load_lds(
      (const __attribute__((address_space(1))) void*)g,
      (__attribute__((address_space(3))) void*)l, 16, 0, 0);
}

// ---------------- weights f32 -> bf16: 4 x 1M-elem slices --------------------
__global__ __launch_bounds__(256) void cvt_kernel(
    const float* __restrict__ Wq, const float* __restrict__ Wk,
    const float* __restrict__ Wv, const float* __restrict__ Wo,
    u16* __restrict__ dst) {
  const int y = blockIdx.y;
  const float* src = (y == 0) ? Wq : (y == 1) ? Wk : (y == 2) ? Wv : Wo;
  u16* d = dst + (size_t)y * MEG;
  int i = (blockIdx.x * 256 + threadIdx.x) * 4;
  float4 f = *(const float4*)(src + i);
  ushort4 o;
  o.x = f2bf(f.x); o.y = f2bf(f.y); o.z = f2bf(f.z); o.w = f2bf(f.w);
  *(ushort4*)(d + i) = o;
}

// -------- batched QKV projection: C = X @ W^T + b, scatter to heads ----------
// X is f32 (conversion fused into A-staging). z=0: Q -> [B,H,S,D];
// z=1: K -> [B,H,S,D]; z=2: V -> [B,H,D,S] (transposed).
// 128x64 tile, BK=64, single-buf; grid (32,16,3) = 1536 blocks for TLP.
__global__ __launch_bounds__(256) void proj_kernel(
    const float* __restrict__ Xq, const float* __restrict__ Xk,
    const float* __restrict__ Xv, const u16* __restrict__ Wc,
    const float* __restrict__ bq, const float* __restrict__ bk,
    const float* __restrict__ bvp,
    u16* __restrict__ Qo, u16* __restrict__ Ko, u16* __restrict__ Vto) {
  __shared__ u16 As[128 * 64];   // 16 KB
  __shared__ u16 Bs[64 * 64];    // 8 KB

  const int tid  = threadIdx.x;
  const int lane = tid & 63;
  const int wid  = tid >> 6;
  const int wm   = wid >> 1, wn = wid & 1;
  const int l15  = lane & 15;
  const int lhi  = lane >> 4;
  const int z    = blockIdx.z;
  const int bm   = blockIdx.x * 128;
  const int bn   = blockIdx.y * 64;

  const float* X = (z == 0) ? Xq : (z == 1) ? Xk : Xv;
  const u16* W = Wc + (size_t)z * (HID * HID);
  const float* bias = (z == 0) ? bq : (z == 1) ? bk : bvp;

  f32x4 acc[4][2];
#pragma unroll
  for (int i = 0; i < 4; i++)
#pragma unroll
    for (int j = 0; j < 2; j++) acc[i][j] = (f32x4){0.f, 0.f, 0.f, 0.f};

  // A-staging map: thread -> (row = tid>>1, 32-col half = tid&1)
  const int arow  = tid >> 1;
  const int acol0 = (tid & 1) * 32;
  // B-staging map (gll16): 8-row groups
  const int lrow  = lane >> 3;
  const int gcol8 = lane & 7;

  for (int t = 0; t < 16; t++) {
    const int k0 = t * 64;
    // ---- B tile via async gll16 (64 rows x 64 cols), inverse-swizzled src ----
#pragma unroll
    for (int c = 0; c < 2; c++) {
      const int row  = c * 32 + wid * 8 + lrow;
      const int scol = (gcol8 ^ (row & 7)) * 8;
      gll16(W + (size_t)(bn + row) * HID + k0 + scol,
            (char*)Bs + c * 4096 + wid * 1024);
    }
    // ---- A tile: f32 load + cvt + swizzled ds_write (fused conversion) ----
    {
      const float* xp = X + (size_t)(bm + arow) * HID + k0 + acol0;
#pragma unroll
      for (int c = 0; c < 4; c++) {
        float4 f0 = ((const float4*)xp)[c * 2 + 0];
        float4 f1 = ((const float4*)xp)[c * 2 + 1];
        ushort4 h0, h1;
        h0.x = f2bf(f0.x); h0.y = f2bf(f0.y); h0.z = f2bf(f0.z); h0.w = f2bf(f0.w);
        h1.x = f2bf(f1.x); h1.y = f2bf(f1.y); h1.z = f2bf(f1.z); h1.w = f2bf(f1.w);
        u16* dst = &As[arow * 64 + swz(arow, acol0 + c * 8)];
        *(ushort4*)(dst + 0) = h0;
        *(ushort4*)(dst + 4) = h1;
      }
    }
    __syncthreads();  // drains gll vmcnt + ds writes
#pragma unroll
    for (int ks = 0; ks < 2; ks++) {
      bf16x8 af[4], bfm[2];
#pragma unroll
      for (int i = 0; i < 4; i++) {
        const int row = wm * 64 + i * 16 + l15;
        af[i] = *(const bf16x8*)&As[row * 64 + swz(row, ks * 32 + lhi * 8)];
      }
#pragma unroll
      for (int j = 0; j < 2; j++) {
        const int row = wn * 32 + j * 16 + l15;
        bfm[j] = *(const bf16x8*)&Bs[row * 64 + swz(row, ks * 32 + lhi * 8)];
      }
#pragma unroll
      for (int i = 0; i < 4; i++)
#pragma unroll
        for (int j = 0; j < 2; j++)
          acc[i][j] = __builtin_amdgcn_mfma_f32_16x16x32_bf16(af[i], bfm[j], acc[i][j], 0, 0, 0);
    }
    __syncthreads();  // all reads done before next stage overwrites
  }

  // epilogue: bias + scatter to heads
  const int bb = bm >> 11;  // tile never crosses batch
#pragma unroll
  for (int j = 0; j < 2; j++) {
    const int n = bn + wn * 32 + j * 16 + l15;
    const float bv_ = bias[n];
    const int h = n >> 6, d = n & 63;
    if (z == 2) {
#pragma unroll
      for (int i = 0; i < 4; i++) {
        const int s0 = (bm + wm * 64 + i * 16 + lhi * 4) & 2047;
        ushort4 t;
        t.x = f2bf(acc[i][j][0] + bv_);
        t.y = f2bf(acc[i][j][1] + bv_);
        t.z = f2bf(acc[i][j][2] + bv_);
        t.w = f2bf(acc[i][j][3] + bv_);
        *(ushort4*)&Vto[((size_t)(bb * NH + h) * HD + d) * SEQ + s0] = t;
      }
    } else {
      u16* O = z ? Ko : Qo;
#pragma unroll
      for (int i = 0; i < 4; i++)
#pragma unroll
        for (int r = 0; r < 4; r++) {
          const int m = bm + wm * 64 + i * 16 + lhi * 4 + r;
          const int s = m & 2047;
          O[(((size_t)(bb * NH + h) * SEQ + s) << 6) + d] = f2bf(acc[i][j][r] + bv_);
        }
    }
  }
}

// ---------------- causal flash attention -------------------------------------
// Q,K: bf16 [B,H,S,D]; Vt: bf16 [B,H,D,S]; out: bf16 [B,S,H*D].
// 512 thr = 2 k-groups x 4 row-waves; swapped QK^T (lane = one q-row).
// T14 issue-early/write-late staging; T13 defer-max; T5 setprio.
__global__ __launch_bounds__(512) void attn_kernel(
    const u16* __restrict__ Q, const u16* __restrict__ K,
    const u16* __restrict__ Vt, u16* __restrict__ Aout) {
  // K[g] @ g*8192, V[g] @ 16384+g*8192 ([64][64] swizzled),
  // Psh[w] @ 32768+wid*2304 ([16][72]). total 51200 B -> 3 blocks/CU.
  __shared__ __align__(16) char pool[51200];

  const int tid  = threadIdx.x;
  const int lane = tid & 63;
  const int wid  = tid >> 6;
  const int rw   = wid & 3;
  const int g    = wid >> 2;
  const int l15  = lane & 15;
  const int lhi  = lane >> 4;

  // XCD-locality remap (T1) + LPT: longest q-tiles first.
  const int flat = blockIdx.x;
  const int slot = flat >> 3;
  const int bh   = (flat & 7) * 4 + (slot & 3);
  const int qt   = 31 - (slot >> 2);
  const int b    = bh >> 4, h = bh & 15;
  const size_t base = (size_t)bh * SEQ * HD;

  u16* Ksh = (u16*)(pool + g * 8192);
  u16* Vsh = (u16*)(pool + 16384 + g * 8192);
  u16* Psh = (u16*)(pool + 32768 + wid * 2304);

  const int qrow = qt * 64 + rw * 16 + l15;
  bf16x8 aq[2];
  aq[0] = *(const bf16x8*)&Q[base + (size_t)qrow * HD + lhi * 8];
  aq[1] = *(const bf16x8*)&Q[base + (size_t)qrow * HD + 32 + lhi * 8];

  f32x4 o[4];
#pragma unroll
  for (int n = 0; n < 4; n++) o[n] = (f32x4){0.f, 0.f, 0.f, 0.f};
  float m_s = -1e30f, l_s = 0.f;

  // staging mapping: 256 thr/group; row 0..63, 16-col chunk
  const int gt   = tid & 255;
  const int srow = gt >> 2;
  const int sd   = (gt & 3) * 16;

  bf16x8 pk0, pk1, pv0, pv1;  // prefetched next-tile K/V (T14)

#define ATTN_LOAD(kt_)                                                            \
  {                                                                               \
    const u16* kp = K + base + (size_t)((kt_) * 64 + srow) * HD + sd;             \
    pk0 = *(const bf16x8*)kp;                                                     \
    pk1 = *(const bf16x8*)(kp + 8);                                               \
    const u16* vp = Vt + base + (size_t)srow * SEQ + (kt_) * 64 + sd;             \
    pv0 = *(const bf16x8*)vp;                                                     \
    pv1 = *(const bf16x8*)(vp + 8);                                               \
  }

  if (g <= qt) ATTN_LOAD(g);

  const int nsteps = qt / 2 + 1;
  for (int it = 0; it < nsteps; ++it) {
    const int kt = 2 * it + g;
    const bool act = (kt <= qt);
    __syncthreads();  // prior tile's LDS reads done
    if (act) {        // write prefetched tile into LDS (swizzled both sides)
      *(bf16x8*)&Ksh[srow * 64 + swz(srow, sd)]     = pk0;
      *(bf16x8*)&Ksh[srow * 64 + swz(srow, sd + 8)] = pk1;
      *(bf16x8*)&Vsh[srow * 64 + swz(srow, sd)]     = pv0;
      *(bf16x8*)&Vsh[srow * 64 + swz(srow, sd + 8)] = pv1;
    }
    const int ktn = kt + 2;
    if (ktn <= qt) ATTN_LOAD(ktn);  // issue-early: lands during compute
    __syncthreads();  // LDS writes visible
    if (act) {
      // S^T = mfma(K, Q): lane l15 = q-row; regs hold k = kt*64 + n*16 + lhi*4 + r
      f32x4 sc[4];
      __builtin_amdgcn_s_setprio(1);
#pragma unroll
      for (int n = 0; n < 4; n++) {
        sc[n] = (f32x4){0.f, 0.f, 0.f, 0.f};
#pragma unroll
        for (int ks = 0; ks < 2; ks++) {
          const int krow = n * 16 + l15;
          bf16x8 bk = *(const bf16x8*)&Ksh[krow * 64 + swz(krow, ks * 32 + lhi * 8)];
          sc[n] = __builtin_amdgcn_mfma_f32_16x16x32_bf16(bk, aq[ks], sc[n], 0, 0, 0);
        }
      }
      __builtin_amdgcn_s_setprio(0);
      if (kt == qt) {  // causal mask on diagonal tile
#pragma unroll
        for (int n = 0; n < 4; n++)
#pragma unroll
          for (int r = 0; r < 4; r++)
            if (kt * 64 + n * 16 + lhi * 4 + r > qrow) sc[n][r] = -1e30f;
      }
      // ---- online softmax, defer-max (T13) ----
      float mx = -1e30f;
#pragma unroll
      for (int n = 0; n < 4; n++)
        mx = fmaxf(mx, fmaxf(fmaxf(sc[n][0], sc[n][1]), fmaxf(sc[n][2], sc[n][3])));
      mx = fmaxf(mx, __shfl_xor(mx, 16, 64));
      mx = fmaxf(mx, __shfl_xor(mx, 32, 64));
      if (__any(mx > m_s + 64.0f)) {  // raw-score THR (e^8 P-bound)
        const float mnew = fmaxf(m_s, mx);
        const float fac = __builtin_amdgcn_exp2f((m_s - mnew) * CEXP);
        l_s *= fac;
        m_s = mnew;
        float facr[4];
#pragma unroll
        for (int r = 0; r < 4; r++) facr[r] = __shfl(fac, lhi * 4 + r, 64);
#pragma unroll
        for (int n = 0; n < 4; n++) {
          o[n][0] *= facr[0]; o[n][1] *= facr[1];
          o[n][2] *= facr[2]; o[n][3] *= facr[3];
        }
      }
      const float nmc = -m_s * CEXP;
      float ps = 0.f;
      u16 pb[4][4];
#pragma unroll
      for (int n = 0; n < 4; n++)
#pragma unroll
        for (int r = 0; r < 4; r++) {
          const float e = __builtin_amdgcn_exp2f(fmaf(sc[n][r], CEXP, nmc));
          ps += e;
          pb[n][r] = f2bf(e);
        }
      ps += __shfl_xor(ps, 16, 64);
      ps += __shfl_xor(ps, 32, 64);
      l_s += ps;
      // P -> per-wave LDS -> A-frag
#pragma unroll
      for (int n = 0; n < 4; n++) {
        ushort4 t; t.x = pb[n][0]; t.y = pb[n][1]; t.z = pb[n][2]; t.w = pb[n][3];
        *(ushort4*)&Psh[l15 * 72 + n * 16 + lhi * 4] = t;
      }
      bf16x8 ap0 = *(const bf16x8*)&Psh[l15 * 72 + lhi * 8];
      bf16x8 ap1 = *(const bf16x8*)&Psh[l15 * 72 + 32 + lhi * 8];
      __builtin_amdgcn_s_setprio(1);
#pragma unroll
      for (int n = 0; n < 4; n++) {
        const int vrow = n * 16 + l15;
        bf16x8 bv0 = *(const bf16x8*)&Vsh[vrow * 64 + swz(vrow, lhi * 8)];
        bf16x8 bv1 = *(const bf16x8*)&Vsh[vrow * 64 + swz(vrow, 32 + lhi * 8)];
        o[n] = __builtin_amdgcn_mfma_f32_16x16x32_bf16(ap0, bv0, o[n], 0, 0, 0);
        o[n] = __builtin_amdgcn_mfma_f32_16x16x32_bf16(ap1, bv1, o[n], 0, 0, 0);
      }
      __builtin_amdgcn_s_setprio(0);
    }
  }
#undef ATTN_LOAD

  __syncthreads();
  float m_o[4], l_o[4];
#pragma unroll
  for (int r = 0; r < 4; r++) {
    m_o[r] = __shfl(m_s, lhi * 4 + r, 64);
    l_o[r] = __shfl(l_s, lhi * 4 + r, 64);
  }

  // merge the two k-groups' partials (pool reused; K/V/P dead)
  f32x4* comb = (f32x4*)pool;
  const int ci = (rw * 64 + lane) * 6;
  if (g == 0) {
#pragma unroll
    for (int n = 0; n < 4; n++) comb[ci + n] = o[n];
    comb[ci + 4] = (f32x4){m_o[0], m_o[1], m_o[2], m_o[3]};
    comb[ci + 5] = (f32x4){l_o[0], l_o[1], l_o[2], l_o[3]};
  }
  __syncthreads();
  if (g == 1) {
    f32x4 m0 = comb[ci + 4];
    f32x4 l0 = comb[ci + 5];
    float a0[4], a1[4], inv[4];
#pragma unroll
    for (int r = 0; r < 4; r++) {
      const float m = fmaxf(m0[r], m_o[r]);
      a0[r] = __builtin_amdgcn_exp2f((m0[r] - m) * CEXP);
      a1[r] = __builtin_amdgcn_exp2f((m_o[r] - m) * CEXP);
      inv[r] = 1.0f / (l0[r] * a0[r] + l_o[r] * a1[r]);
    }
#pragma unroll
    for (int n = 0; n < 4; n++) {
      f32x4 o0 = comb[ci + n];
#pragma unroll
      for (int r = 0; r < 4; r++) {
        const int rowg = qt * 64 + rw * 16 + lhi * 4 + r;
        const float val = (o0[r] * a0[r] + o[n][r] * a1[r]) * inv[r];
        Aout[(((size_t)(b * SEQ + rowg)) << 10) + h * 64 + n * 16 + l15] = f2bf(val);
      }
    }
  }
}

// ---------------- out projection: f32 out = Ab @ Wo^T + bo -------------------
// 128x64 tile, BK=64, m97 single-buffer (24 KB). grid (32,16).
__global__ __launch_bounds__(256) void oproj_kernel(
    const u16* __restrict__ X, const u16* __restrict__ W,
    const float* __restrict__ bias, float* __restrict__ Out) {
  __shared__ u16 As[128 * 64];
  __shared__ u16 Bs[64 * 64];

  const int tid  = threadIdx.x;
  const int lane = tid & 63;
  const int wid  = tid >> 6;
  const int wm   = wid >> 1, wn = wid & 1;
  const int l15  = lane & 15;
  const int lhi  = lane >> 4;
  const int bm   = blockIdx.x * 128;
  const int bn   = blockIdx.y * 64;

  f32x4 acc[4][2];
#pragma unroll
  for (int i = 0; i < 4; i++)
#pragma unroll
    for (int j = 0; j < 2; j++) acc[i][j] = (f32x4){0.f, 0.f, 0.f, 0.f};

  const int lrow  = lane >> 3;
  const int gcol8 = lane & 7;

  for (int t = 0; t < 16; t++) {
    const int k0 = t * 64;
#pragma unroll
    for (int c = 0; c < 4; c++) {
      const int row  = c * 32 + wid * 8 + lrow;
      const int scol = (gcol8 ^ (row & 7)) * 8;
      gll16(X + (size_t)(bm + row) * HID + k0 + scol,
            (char*)As + c * 4096 + wid * 1024);
      if (c < 2)
        gll16(W + (size_t)(bn + row) * HID + k0 + scol,
              (char*)Bs + c * 4096 + wid * 1024);
    }
    __syncthreads();
#pragma unroll
    for (int ks = 0; ks < 2; ks++) {
      bf16x8 af[4], bfm[2];
#pragma unroll
      for (int i = 0; i < 4; i++) {
        const int row = wm * 64 + i * 16 + l15;
        af[i] = *(const bf16x8*)&As[row * 64 + swz(row, ks * 32 + lhi * 8)];
      }
#pragma unroll
      for (int j = 0; j < 2; j++) {
        const int row = wn * 32 + j * 16 + l15;
        bfm[j] = *(const bf16x8*)&Bs[row * 64 + swz(row, ks * 32 + lhi * 8)];
      }
#pragma unroll
      for (int i = 0; i < 4; i++)
#pragma unroll
        for (int j = 0; j < 2; j++)
          acc[i][j] = __builtin_amdgcn_mfma_f32_16x16x32_bf16(af[i], bfm[j], acc[i][j], 0, 0, 0);
    }
    __syncthreads();
  }

#pragma unroll
  for (int j = 0; j < 2; j++) {
    const int n = bn + wn * 32 + j * 16 + l15;
    const float bv_ = bias[n];
#pragma unroll
    for (int i = 0; i < 4; i++)
#pragma unroll
      for (int r = 0; r < 4; r++) {
        const int m = bm + wm * 64 + i * 16 + lhi * 4 + r;
        Out[(size_t)m * HID + n] = acc[i][j][r] + bv_;
      }
  }
}

// ---------------- launch ------------------------------------------------------
extern "C" void kernel_launch(void* const* d_in, const int* in_sizes, int n_in,
                              void* d_out, int out_size, void* d_ws, size_t ws_size,
                              hipStream_t stream) {
  const float* q  = (const float*)d_in[0];
  const float* k  = (const float*)d_in[1];
  const float* v  = (const float*)d_in[2];
  const float* Wq = (const float*)d_in[3];
  const float* bq = (const float*)d_in[4];
  const float* Wk = (const float*)d_in[5];
  const float* bk = (const float*)d_in[6];
  const float* Wv = (const float*)d_in[7];
  const float* bv = (const float*)d_in[8];
  const float* Wo = (const float*)d_in[9];
  const float* bo = (const float*)d_in[10];

  u16* ws   = (u16*)d_ws;
  u16* wqkv = ws;                     // Wq,Wk,Wv bf16 @ 0,1M,2M
  u16* wob  = ws + 3u * MEG;          // Wo bf16
  u16* Qb   = ws + 4u * MEG;          // [B,H,S,D]
  u16* Kb   = ws + 8u * MEG;          // [B,H,S,D]
  u16* Vtb  = ws + 12u * MEG;         // [B,H,D,S]
  u16* Ab   = ws + 16u * MEG;         // [B,S,HID]

  cvt_kernel<<<dim3(1024, 4), 256, 0, stream>>>(Wq, Wk, Wv, Wo, ws);

  proj_kernel<<<dim3(32, 16, 3), 256, 0, stream>>>(q, k, v, wqkv, bq, bk, bv,
                                                   Qb, Kb, Vtb);

  attn_kernel<<<dim3(1024), 512, 0, stream>>>(Qb, Kb, Vtb, Ab);

  oproj_kernel<<<dim3(32, 16), 256, 0, stream>>>(Ab, wob, bo, (float*)d_out);
}

// Round 9
// 110.909 us; speedup vs baseline: 1.5004x; 1.5004x over previous
//
#include <hip/hip_runtime.h>
#include <hip/hip_bf16.h>

// MHA forward, MI355X gfx950.
// cvt (weights -> bf16) -> batched QKV proj GEMM (128x128 single-buf, A staged
// as f32 via global_load_lds + cvt at frag read, swizzled LDS) -> causal flash
// attn (swapped-QK softmax, T13/T5/T14, XCD remap + LPT) -> out GEMM.
// HIDDEN=1024, HEADS=16, HEAD_DIM=64, B=2, S=2048.

typedef __attribute__((ext_vector_type(4))) float f32x4;
typedef __attribute__((ext_vector_type(8))) short bf16x8;
typedef unsigned short u16;

#define SEQ   2048
#define NH    16
#define HD    64
#define HID   1024
#define CEXP  0.1803368801f  // 0.125 * log2(e)
#define MEG   1048576u

// HW round-to-nearest-even f32->bf16.
static __device__ __forceinline__ u16 f2bf(float f) {
  union { __hip_bfloat16 h; u16 u; } c;
  c.h = __float2bfloat16(f);
  return c.u;
}

// XOR swizzle on 8-elem bf16 chunks within a 64-elem row (T2, G4).
static __device__ __forceinline__ int swz(int row, int col8) {
  return col8 ^ ((row & 7) << 3);
}

// 4-bit swizzle for f32 rows of 64 (16 x 16B chunks): 16 rows -> 16 slots.
static __device__ __forceinline__ int swze(int row) {
  return ((row & 7) << 1) | ((row >> 3) & 1);
}

// async global->LDS, 16B/lane; lds dest wave-uniform base (guide §5).
static __device__ __forceinline__ void gll16(const void* g, void* l) {
  __builtin_amdgcn_global_load_lds(
      (const __attribute__((address_space(1))) void*)g,
      (__attribute__((address_space(3))) void*)l, 16, 0, 0);
}

// ---------------- weights f32 -> bf16: 4 x 1M-elem slices --------------------
__global__ __launch_bounds__(256) void cvt_kernel(
    const float* __restrict__ Wq, const float* __restrict__ Wk,
    const float* __restrict__ Wv, const float* __restrict__ Wo,
    u16* __restrict__ dst) {
  const int y = blockIdx.y;
  const float* src = (y == 0) ? Wq : (y == 1) ? Wk : (y == 2) ? Wv : Wo;
  u16* d = dst + (size_t)y * MEG;
  int i = (blockIdx.x * 256 + threadIdx.x) * 4;
  float4 f = *(const float4*)(src + i);
  ushort4 o;
  o.x = f2bf(f.x); o.y = f2bf(f.y); o.z = f2bf(f.z); o.w = f2bf(f.w);
  *(ushort4*)(d + i) = o;
}

// -------- batched QKV projection: C = X @ W^T + b, scatter to heads ----------
// X is f32, staged via async gll16 into f32 LDS; bf16 cvt at frag read.
// z=0: Q -> [B,H,S,D]; z=1: K -> [B,H,S,D]; z=2: V -> [B,H,D,S] (transposed).
// 128x128 tile, BK=64, single-buf (48 KB -> 3 blocks/CU), grid (32,8,3).
__global__ __launch_bounds__(256) void proj_kernel(
    const float* __restrict__ Xq, const float* __restrict__ Xk,
    const float* __restrict__ Xv, const u16* __restrict__ Wc,
    const float* __restrict__ bq, const float* __restrict__ bk,
    const float* __restrict__ bvp,
    u16* __restrict__ Qo, u16* __restrict__ Ko, u16* __restrict__ Vto) {
  __shared__ float Asf[128 * 64];  // 32 KB, [row][64 f32] chunk-swizzled
  __shared__ u16   Bs[128 * 64];   // 16 KB, [row][64 bf16] swizzled

  const int tid  = threadIdx.x;
  const int lane = tid & 63;
  const int wid  = tid >> 6;
  const int wm   = wid >> 1, wn = wid & 1;
  const int l15  = lane & 15;
  const int lhi  = lane >> 4;
  const int z    = blockIdx.z;
  const int bm   = blockIdx.x * 128;
  const int bn   = blockIdx.y * 128;

  const float* X = (z == 0) ? Xq : (z == 1) ? Xk : Xv;
  const u16* W = Wc + (size_t)z * (HID * HID);
  const float* bias = (z == 0) ? bq : (z == 1) ? bk : bvp;

  f32x4 acc[4][4];
#pragma unroll
  for (int i = 0; i < 4; i++)
#pragma unroll
    for (int j = 0; j < 4; j++) acc[i][j] = (f32x4){0.f, 0.f, 0.f, 0.f};

  // A-staging: 8 gll16/wave, each covers 4 rows (16 lanes x 16B per row)
  const int arow_off = lane >> 4;      // 0..3
  const int achunk   = lane & 15;      // 16B chunk within 256B row
  // B-staging: 4 gll16/wave, each covers 8 rows (8 lanes x 16B per row)
  const int lrow  = lane >> 3;         // 0..7
  const int gcol8 = lane & 7;

  for (int t = 0; t < 16; t++) {
    const int k0 = t * 64;
    // ---- A tile f32 via async gll16, inverse-swizzled source ----
#pragma unroll
    for (int c = 0; c < 8; c++) {
      const int row = wid * 32 + c * 4 + arow_off;
      gll16(X + (size_t)(bm + row) * HID + k0 + ((achunk ^ swze(row)) << 2),
            (char*)Asf + wid * 8192 + c * 1024);
    }
    // ---- B tile bf16 via async gll16 ----
#pragma unroll
    for (int c = 0; c < 4; c++) {
      const int row = c * 32 + wid * 8 + lrow;
      gll16(W + (size_t)(bn + row) * HID + k0 + (gcol8 ^ (row & 7)) * 8,
            (char*)Bs + c * 4096 + wid * 1024);
    }
    __syncthreads();  // drains gll vmcnt
#pragma unroll
    for (int ks = 0; ks < 2; ks++) {
      bf16x8 af[4], bfm[4];
#pragma unroll
      for (int i = 0; i < 4; i++) {
        const int row = wm * 64 + i * 16 + l15;
        const int e   = swze(row);
        const int c0  = ks * 8 + lhi * 2;
        f32x4 flo = *(const f32x4*)&Asf[row * 64 + ((c0 ^ e) << 2)];
        f32x4 fhi = *(const f32x4*)&Asf[row * 64 + (((c0 + 1) ^ e) << 2)];
        union { u16 a[8]; bf16x8 v; } u;
        u.a[0] = f2bf(flo[0]); u.a[1] = f2bf(flo[1]);
        u.a[2] = f2bf(flo[2]); u.a[3] = f2bf(flo[3]);
        u.a[4] = f2bf(fhi[0]); u.a[5] = f2bf(fhi[1]);
        u.a[6] = f2bf(fhi[2]); u.a[7] = f2bf(fhi[3]);
        af[i] = u.v;
      }
#pragma unroll
      for (int j = 0; j < 4; j++) {
        const int row = wn * 64 + j * 16 + l15;
        bfm[j] = *(const bf16x8*)&Bs[row * 64 + swz(row, ks * 32 + lhi * 8)];
      }
#pragma unroll
      for (int i = 0; i < 4; i++)
#pragma unroll
        for (int j = 0; j < 4; j++)
          acc[i][j] = __builtin_amdgcn_mfma_f32_16x16x32_bf16(af[i], bfm[j], acc[i][j], 0, 0, 0);
    }
    __syncthreads();  // all reads done before next stage overwrites
  }

  // epilogue: bias + scatter to heads
  const int bb = bm >> 11;  // tile never crosses batch
#pragma unroll
  for (int j = 0; j < 4; j++) {
    const int n = bn + wn * 64 + j * 16 + l15;
    const float bv_ = bias[n];
    const int h = n >> 6, d = n & 63;
    if (z == 2) {
#pragma unroll
      for (int i = 0; i < 4; i++) {
        const int s0 = (bm + wm * 64 + i * 16 + lhi * 4) & 2047;
        ushort4 t;
        t.x = f2bf(acc[i][j][0] + bv_);
        t.y = f2bf(acc[i][j][1] + bv_);
        t.z = f2bf(acc[i][j][2] + bv_);
        t.w = f2bf(acc[i][j][3] + bv_);
        *(ushort4*)&Vto[((size_t)(bb * NH + h) * HD + d) * SEQ + s0] = t;
      }
    } else {
      u16* O = z ? Ko : Qo;
#pragma unroll
      for (int i = 0; i < 4; i++)
#pragma unroll
        for (int r = 0; r < 4; r++) {
          const int m = bm + wm * 64 + i * 16 + lhi * 4 + r;
          const int s = m & 2047;
          O[(((size_t)(bb * NH + h) * SEQ + s) << 6) + d] = f2bf(acc[i][j][r] + bv_);
        }
    }
  }
}

// ---------------- causal flash attention -------------------------------------
// Q,K: bf16 [B,H,S,D]; Vt: bf16 [B,H,D,S]; out: bf16 [B,S,H*D].
// 512 thr = 2 k-groups x 4 row-waves; swapped QK^T (lane = one q-row).
// T14 issue-early/write-late staging; T13 defer-max; T5 setprio.
__global__ __launch_bounds__(512) void attn_kernel(
    const u16* __restrict__ Q, const u16* __restrict__ K,
    const u16* __restrict__ Vt, u16* __restrict__ Aout) {
  __shared__ __align__(16) char pool[51200];

  const int tid  = threadIdx.x;
  const int lane = tid & 63;
  const int wid  = tid >> 6;
  const int rw   = wid & 3;
  const int g    = wid >> 2;
  const int l15  = lane & 15;
  const int lhi  = lane >> 4;

  // XCD-locality remap (T1) + LPT: longest q-tiles first.
  const int flat = blockIdx.x;
  const int slot = flat >> 3;
  const int bh   = (flat & 7) * 4 + (slot & 3);
  const int qt   = 31 - (slot >> 2);
  const int b    = bh >> 4, h = bh & 15;
  const size_t base = (size_t)bh * SEQ * HD;

  u16* Ksh = (u16*)(pool + g * 8192);
  u16* Vsh = (u16*)(pool + 16384 + g * 8192);
  u16* Psh = (u16*)(pool + 32768 + wid * 2304);

  const int qrow = qt * 64 + rw * 16 + l15;
  bf16x8 aq[2];
  aq[0] = *(const bf16x8*)&Q[base + (size_t)qrow * HD + lhi * 8];
  aq[1] = *(const bf16x8*)&Q[base + (size_t)qrow * HD + 32 + lhi * 8];

  f32x4 o[4];
#pragma unroll
  for (int n = 0; n < 4; n++) o[n] = (f32x4){0.f, 0.f, 0.f, 0.f};
  float m_s = -1e30f, l_s = 0.f;

  const int gt   = tid & 255;
  const int srow = gt >> 2;
  const int sd   = (gt & 3) * 16;

  bf16x8 pk0, pk1, pv0, pv1;  // prefetched next-tile K/V (T14)

#define ATTN_LOAD(kt_)                                                            \
  {                                                                               \
    const u16* kp = K + base + (size_t)((kt_) * 64 + srow) * HD + sd;             \
    pk0 = *(const bf16x8*)kp;                                                     \
    pk1 = *(const bf16x8*)(kp + 8);                                               \
    const u16* vp = Vt + base + (size_t)srow * SEQ + (kt_) * 64 + sd;             \
    pv0 = *(const bf16x8*)vp;                                                     \
    pv1 = *(const bf16x8*)(vp + 8);                                               \
  }

  if (g <= qt) ATTN_LOAD(g);

  const int nsteps = qt / 2 + 1;
  for (int it = 0; it < nsteps; ++it) {
    const int kt = 2 * it + g;
    const bool act = (kt <= qt);
    __syncthreads();  // prior tile's LDS reads done
    if (act) {        // write prefetched tile into LDS (swizzled both sides)
      *(bf16x8*)&Ksh[srow * 64 + swz(srow, sd)]     = pk0;
      *(bf16x8*)&Ksh[srow * 64 + swz(srow, sd + 8)] = pk1;
      *(bf16x8*)&Vsh[srow * 64 + swz(srow, sd)]     = pv0;
      *(bf16x8*)&Vsh[srow * 64 + swz(srow, sd + 8)] = pv1;
    }
    const int ktn = kt + 2;
    if (ktn <= qt) ATTN_LOAD(ktn);  // issue-early: lands during compute
    __syncthreads();  // LDS writes visible
    if (act) {
      f32x4 sc[4];
      __builtin_amdgcn_s_setprio(1);
#pragma unroll
      for (int n = 0; n < 4; n++) {
        sc[n] = (f32x4){0.f, 0.f, 0.f, 0.f};
#pragma unroll
        for (int ks = 0; ks < 2; ks++) {
          const int krow = n * 16 + l15;
          bf16x8 bk = *(const bf16x8*)&Ksh[krow * 64 + swz(krow, ks * 32 + lhi * 8)];
          sc[n] = __builtin_amdgcn_mfma_f32_16x16x32_bf16(bk, aq[ks], sc[n], 0, 0, 0);
        }
      }
      __builtin_amdgcn_s_setprio(0);
      if (kt == qt) {  // causal mask on diagonal tile
#pragma unroll
        for (int n = 0; n < 4; n++)
#pragma unroll
          for (int r = 0; r < 4; r++)
            if (kt * 64 + n * 16 + lhi * 4 + r > qrow) sc[n][r] = -1e30f;
      }
      // ---- online softmax, defer-max (T13) ----
      float mx = -1e30f;
#pragma unroll
      for (int n = 0; n < 4; n++)
        mx = fmaxf(mx, fmaxf(fmaxf(sc[n][0], sc[n][1]), fmaxf(sc[n][2], sc[n][3])));
      mx = fmaxf(mx, __shfl_xor(mx, 16, 64));
      mx = fmaxf(mx, __shfl_xor(mx, 32, 64));
      if (__any(mx > m_s + 64.0f)) {  // raw-score THR (e^8 P-bound)
        const float mnew = fmaxf(m_s, mx);
        const float fac = __builtin_amdgcn_exp2f((m_s - mnew) * CEXP);
        l_s *= fac;
        m_s = mnew;
        float facr[4];
#pragma unroll
        for (int r = 0; r < 4; r++) facr[r] = __shfl(fac, lhi * 4 + r, 64);
#pragma unroll
        for (int n = 0; n < 4; n++) {
          o[n][0] *= facr[0]; o[n][1] *= facr[1];
          o[n][2] *= facr[2]; o[n][3] *= facr[3];
        }
      }
      const float nmc = -m_s * CEXP;
      float ps = 0.f;
      u16 pb[4][4];
#pragma unroll
      for (int n = 0; n < 4; n++)
#pragma unroll
        for (int r = 0; r < 4; r++) {
          const float e = __builtin_amdgcn_exp2f(fmaf(sc[n][r], CEXP, nmc));
          ps += e;
          pb[n][r] = f2bf(e);
        }
      ps += __shfl_xor(ps, 16, 64);
      ps += __shfl_xor(ps, 32, 64);
      l_s += ps;
      // P -> per-wave LDS -> A-frag
#pragma unroll
      for (int n = 0; n < 4; n++) {
        ushort4 t; t.x = pb[n][0]; t.y = pb[n][1]; t.z = pb[n][2]; t.w = pb[n][3];
        *(ushort4*)&Psh[l15 * 72 + n * 16 + lhi * 4] = t;
      }
      bf16x8 ap0 = *(const bf16x8*)&Psh[l15 * 72 + lhi * 8];
      bf16x8 ap1 = *(const bf16x8*)&Psh[l15 * 72 + 32 + lhi * 8];
      __builtin_amdgcn_s_setprio(1);
#pragma unroll
      for (int n = 0; n < 4; n++) {
        const int vrow = n * 16 + l15;
        bf16x8 bv0 = *(const bf16x8*)&Vsh[vrow * 64 + swz(vrow, lhi * 8)];
        bf16x8 bv1 = *(const bf16x8*)&Vsh[vrow * 64 + swz(vrow, 32 + lhi * 8)];
        o[n] = __builtin_amdgcn_mfma_f32_16x16x32_bf16(ap0, bv0, o[n], 0, 0, 0);
        o[n] = __builtin_amdgcn_mfma_f32_16x16x32_bf16(ap1, bv1, o[n], 0, 0, 0);
      }
      __builtin_amdgcn_s_setprio(0);
    }
  }
#undef ATTN_LOAD

  __syncthreads();
  float m_o[4], l_o[4];
#pragma unroll
  for (int r = 0; r < 4; r++) {
    m_o[r] = __shfl(m_s, lhi * 4 + r, 64);
    l_o[r] = __shfl(l_s, lhi * 4 + r, 64);
  }

  f32x4* comb = (f32x4*)pool;
  const int ci = (rw * 64 + lane) * 6;
  if (g == 0) {
#pragma unroll
    for (int n = 0; n < 4; n++) comb[ci + n] = o[n];
    comb[ci + 4] = (f32x4){m_o[0], m_o[1], m_o[2], m_o[3]};
    comb[ci + 5] = (f32x4){l_o[0], l_o[1], l_o[2], l_o[3]};
  }
  __syncthreads();
  if (g == 1) {
    f32x4 m0 = comb[ci + 4];
    f32x4 l0 = comb[ci + 5];
    float a0[4], a1[4], inv[4];
#pragma unroll
    for (int r = 0; r < 4; r++) {
      const float m = fmaxf(m0[r], m_o[r]);
      a0[r] = __builtin_amdgcn_exp2f((m0[r] - m) * CEXP);
      a1[r] = __builtin_amdgcn_exp2f((m_o[r] - m) * CEXP);
      inv[r] = 1.0f / (l0[r] * a0[r] + l_o[r] * a1[r]);
    }
#pragma unroll
    for (int n = 0; n < 4; n++) {
      f32x4 o0 = comb[ci + n];
#pragma unroll
      for (int r = 0; r < 4; r++) {
        const int rowg = qt * 64 + rw * 16 + lhi * 4 + r;
        const float val = (o0[r] * a0[r] + o[n][r] * a1[r]) * inv[r];
        Aout[(((size_t)(b * SEQ + rowg)) << 10) + h * 64 + n * 16 + l15] = f2bf(val);
      }
    }
  }
}

// ---------------- out projection: f32 out = Ab @ Wo^T + bo -------------------
// 128x64 tile, BK=64, m97 single-buffer (24 KB). grid (32,16).
__global__ __launch_bounds__(256) void oproj_kernel(
    const u16* __restrict__ X, const u16* __restrict__ W,
    const float* __restrict__ bias, float* __restrict__ Out) {
  __shared__ u16 As[128 * 64];
  __shared__ u16 Bs[64 * 64];

  const int tid  = threadIdx.x;
  const int lane = tid & 63;
  const int wid  = tid >> 6;
  const int wm   = wid >> 1, wn = wid & 1;
  const int l15  = lane & 15;
  const int lhi  = lane >> 4;
  const int bm   = blockIdx.x * 128;
  const int bn   = blockIdx.y * 64;

  f32x4 acc[4][2];
#pragma unroll
  for (int i = 0; i < 4; i++)
#pragma unroll
    for (int j = 0; j < 2; j++) acc[i][j] = (f32x4){0.f, 0.f, 0.f, 0.f};

  const int lrow  = lane >> 3;
  const int gcol8 = lane & 7;

  for (int t = 0; t < 16; t++) {
    const int k0 = t * 64;
#pragma unroll
    for (int c = 0; c < 4; c++) {
      const int row  = c * 32 + wid * 8 + lrow;
      const int scol = (gcol8 ^ (row & 7)) * 8;
      gll16(X + (size_t)(bm + row) * HID + k0 + scol,
            (char*)As + c * 4096 + wid * 1024);
      if (c < 2)
        gll16(W + (size_t)(bn + row) * HID + k0 + scol,
              (char*)Bs + c * 4096 + wid * 1024);
    }
    __syncthreads();
#pragma unroll
    for (int ks = 0; ks < 2; ks++) {
      bf16x8 af[4], bfm[2];
#pragma unroll
      for (int i = 0; i < 4; i++) {
        const int row = wm * 64 + i * 16 + l15;
        af[i] = *(const bf16x8*)&As[row * 64 + swz(row, ks * 32 + lhi * 8)];
      }
#pragma unroll
      for (int j = 0; j < 2; j++) {
        const int row = wn * 32 + j * 16 + l15;
        bfm[j] = *(const bf16x8*)&Bs[row * 64 + swz(row, ks * 32 + lhi * 8)];
      }
#pragma unroll
      for (int i = 0; i < 4; i++)
#pragma unroll
        for (int j = 0; j < 2; j++)
          acc[i][j] = __builtin_amdgcn_mfma_f32_16x16x32_bf16(af[i], bfm[j], acc[i][j], 0, 0, 0);
    }
    __syncthreads();
  }

#pragma unroll
  for (int j = 0; j < 2; j++) {
    const int n = bn + wn * 32 + j * 16 + l15;
    const float bv_ = bias[n];
#pragma unroll
    for (int i = 0; i < 4; i++)
#pragma unroll
      for (int r = 0; r < 4; r++) {
        const int m = bm + wm * 64 + i * 16 + lhi * 4 + r;
        Out[(size_t)m * HID + n] = acc[i][j][r] + bv_;
      }
  }
}

// ---------------- launch ------------------------------------------------------
extern "C" void kernel_launch(void* const* d_in, const int* in_sizes, int n_in,
                              void* d_out, int out_size, void* d_ws, size_t ws_size,
                              hipStream_t stream) {
  const float* q  = (const float*)d_in[0];
  const float* k  = (const float*)d_in[1];
  const float* v  = (const float*)d_in[2];
  const float* Wq = (const float*)d_in[3];
  const float* bq = (const float*)d_in[4];
  const float* Wk = (const float*)d_in[5];
  const float* bk = (const float*)d_in[6];
  const float* Wv = (const float*)d_in[7];
  const float* bv = (const float*)d_in[8];
  const float* Wo = (const float*)d_in[9];
  const float* bo = (const float*)d_in[10];

  u16* ws   = (u16*)d_ws;
  u16* wqkv = ws;                     // Wq,Wk,Wv bf16 @ 0,1M,2M
  u16* wob  = ws + 3u * MEG;          // Wo bf16
  u16* Qb   = ws + 4u * MEG;          // [B,H,S,D]
  u16* Kb   = ws + 8u * MEG;          // [B,H,S,D]
  u16* Vtb  = ws + 12u * MEG;         // [B,H,D,S]
  u16* Ab   = ws + 16u * MEG;         // [B,S,HID]

  cvt_kernel<<<dim3(1024, 4), 256, 0, stream>>>(Wq, Wk, Wv, Wo, ws);

  proj_kernel<<<dim3(32, 8, 3), 256, 0, stream>>>(q, k, v, wqkv, bq, bk, bv,
                                                  Qb, Kb, Vtb);

  attn_kernel<<<dim3(1024), 512, 0, stream>>>(Qb, Kb, Vtb, Ab);

  oproj_kernel<<<dim3(32, 16), 256, 0, stream>>>(Ab, wob, bo, (float*)d_out);
}